// Round 1
// 457.401 us; speedup vs baseline: 1.0093x; 1.0093x over previous
//
#include <hip/hip_runtime.h>

#define ROWS 8192
#define COLS 8192
#define TPB  256
#define EPT  32   // elements per thread (COLS / TPB)
#define VPT  8    // float4 chunks per thread
#define NW   4    // waves per block

// Monotonic float->uint key: order of keys == order of floats.
__device__ __forceinline__ unsigned f2k(float x) {
    unsigned u = __float_as_uint(x);
    return (u & 0x80000000u) ? ~u : (u | 0x80000000u);
}
__device__ __forceinline__ float k2f(unsigned k) {
    unsigned u = (k & 0x80000000u) ? (k & 0x7FFFFFFFu) : ~k;
    return __uint_as_float(u);
}

__global__ __launch_bounds__(TPB, 4)
void rsoftmax_kernel(const float* __restrict__ in,
                     const float* __restrict__ rate_p,
                     float* __restrict__ out)
{
    const int t    = threadIdx.x;
    const int lane = t & 63;
    const int wave = t >> 6;
    const int row  = blockIdx.x;
    const float4* in4  = (const float4*)(in  + (size_t)row * COLS);
    float4*       out4 = (float4*)      (out + (size_t)row * COLS);

    // ---- load this thread's 32 elements into registers as ordered keys ----
    unsigned key[EPT];
    #pragma unroll
    for (int j = 0; j < VPT; ++j) {
        float4 v = in4[t + j * TPB];           // coalesced 16B/lane
        key[4*j+0] = f2k(v.x);
        key[4*j+1] = f2k(v.y);
        key[4*j+2] = f2k(v.z);
        key[4*j+3] = f2k(v.w);
    }

    // ---- rank to select: thresh = sorted_desc[idx], i.e. (idx+1)-th largest ----
    float rate = rate_p[0];
    rate = fminf(fmaxf(rate, 0.0f), 1.0f);
    int idx = (int)(rate * (float)COLS);       // trunc, like astype(int32)
    if (idx > COLS - 1) idx = COLS - 1;        // jnp.take clips
    if (idx < 0) idx = 0;

    __shared__ unsigned sHistW[NW][256];       // wave-private histograms (4 KB)
    __shared__ unsigned sWaveTot[NW];
    __shared__ unsigned sK, sPfx;
    __shared__ float    sSum[NW];
    __shared__ float    sInv;

    if (t == 0) { sK = (unsigned)(idx + 1); sPfx = 0u; }

    // ---- MSB-first 4x8-bit radix select for the k-th largest key ----
    // Per pass: 3 barriers total (vs ~21 in the scan-in-LDS version).
    #pragma unroll
    for (int pass = 0; pass < 4; ++pass) {
        const int      s      = 24 - 8 * pass;
        const unsigned himask = (pass == 0) ? 0u : (0xFFFFFFFFu << (s + 8));

        __syncthreads();                       // sPfx/sK visible; prior hist reads done
        const unsigned pfx = sPfx;
        const unsigned kk  = sK;

        // zero own wave's histogram — wave-local, no cross-wave sync needed
        #pragma unroll
        for (int i = 0; i < 4; ++i) sHistW[wave][lane + 64*i] = 0u;

        #pragma unroll
        for (int j = 0; j < EPT; ++j) {
            if (((key[j] ^ pfx) & himask) == 0u)
                atomicAdd(&sHistW[wave][(key[j] >> s) & 0xFFu], 1u);
        }
        __syncthreads();                       // all wave hists complete

        // cross-wave bin reduce: thread t owns bin t (conflict-free, stride-1)
        const unsigned h = sHistW[0][t] + sHistW[1][t] + sHistW[2][t] + sHistW[3][t];

        // in-register suffix sum across the wave's 64 bins (no LDS, no barriers)
        unsigned v = h;
        #pragma unroll
        for (int off = 1; off < 64; off <<= 1) {
            unsigned u = __shfl_down(v, off, 64);
            v += (lane + off < 64) ? u : 0u;   // lane l: sum of bins l..63 (this wave)
        }
        if (lane == 0) sWaveTot[wave] = v;     // wave total
        __syncthreads();

        unsigned above = 0u;                   // totals of higher-bin waves
        #pragma unroll
        for (int w = 0; w < NW; ++w)
            if (w > wave) above += sWaveTot[w];

        const unsigned st = v + above;         // suffix[t]  = #elems with digit >= t
        const unsigned sn = st - h;            // suffix[t+1]
        if (st >= kk && sn < kk) {             // unique crossing bin
            sPfx = pfx | ((unsigned)t << s);
            sK   = kk - sn;
        }
    }
    __syncthreads();
    const float thr = k2f(sPfx);

    // ---- weighted-exp values, cached in registers; wave+block sum ----
    float wx[EPT];
    float lsum = 0.0f;
    #pragma unroll
    for (int j = 0; j < EPT; ++j) {
        float x = k2f(key[j]);
        float e = fmaxf(x - thr, 0.0f) * __expf(x);
        wx[j] = e;
        lsum += e;
    }
    #pragma unroll
    for (int off = 32; off > 0; off >>= 1)
        lsum += __shfl_down(lsum, off, 64);
    if (lane == 0) sSum[wave] = lsum;
    __syncthreads();
    if (t == 0) sInv = 1.0f / (sSum[0] + sSum[1] + sSum[2] + sSum[3]);
    __syncthreads();
    const float inv = sInv;

    // ---- normalized write, float4-coalesced ----
    #pragma unroll
    for (int j = 0; j < VPT; ++j) {
        float4 o;
        o.x = wx[4*j+0] * inv;
        o.y = wx[4*j+1] * inv;
        o.z = wx[4*j+2] * inv;
        o.w = wx[4*j+3] * inv;
        out4[t + j * TPB] = o;
    }
}

extern "C" void kernel_launch(void* const* d_in, const int* in_sizes, int n_in,
                              void* d_out, int out_size, void* d_ws, size_t ws_size,
                              hipStream_t stream)
{
    const float* in   = (const float*)d_in[0];
    const float* rate = (const float*)d_in[1];
    float*       out  = (float*)d_out;
    rsoftmax_kernel<<<dim3(ROWS), dim3(TPB), 0, stream>>>(in, rate, out);
}